// Round 10
// baseline (121.524 us; speedup 1.0000x reference)
//
#include <hip/hip_runtime.h>
#include <math.h>

#define NB 16384
typedef _Float16 f16;
typedef _Float16 f16x8 __attribute__((ext_vector_type(8)));
typedef _Float16 f16x4 __attribute__((ext_vector_type(4)));
typedef float f32x4 __attribute__((ext_vector_type(4)));

__device__ __forceinline__ float fast_sig(float v)  { return __builtin_amdgcn_rcpf(1.0f + __expf(-v)); }
__device__ __forceinline__ float fast_tanh(float v) { return 1.0f - 2.0f * __builtin_amdgcn_rcpf(1.0f + __expf(2.0f * v)); }

#define MFMA16(A, B, C) __builtin_amdgcn_mfma_f32_16x16x32_f16(A, B, C, 0, 0, 0)

// ---------------- kernel 1: es = mean_L(enc) (r8 version) -----------------------
// DIAGNOSTIC ROUND: launched TWICE (idempotent) so dur_total - 91.4us = es time.
__global__ __launch_bounds__(256) void es_kernel(
    const float* __restrict__ enc, float* __restrict__ es)
{
    const int u = blockIdx.x * 256 + threadIdx.x;    // float4 unit
    const float4* e4 = (const float4*)enc;
    float ax = 0.f, ay = 0.f, az = 0.f, aw = 0.f;
    #pragma unroll 8
    for (int L = 0; L < 48; ++L) {
        const float4 v = e4[(size_t)L * (NB * 15) + u];
        ax += v.x; ay += v.y; az += v.z; aw += v.w;
    }
    const float s = 1.f / 48.f;
    float4 r; r.x = ax * s; r.y = ay * s; r.z = az * s; r.w = aw * s;
    ((float4*)es)[u] = r;
}

// ---------------- kernel 2: decode, DUAL full 16-row tiles per wave -------------
// (r8-verified body, byte-identical.) 32 batch rows / wave. Weights persistent
// in VGPRs as f16 B-fragments; activations round-trip through tiny LDS.
// x16 row layout (72 halves, 144B stride): [0..3]=rin [4..33]=enh [34..63]=h [64..71]=scratch
__global__ __launch_bounds__(64, 1) void decoder_kernel(
    const float* __restrict__ y,      // [B,13,4]
    const float* __restrict__ enc,    // [48,B,60]
    const float* __restrict__ esrc,   // [B,60] premeaned (or null -> fused scan)
    const float* __restrict__ hidden, // [B,30]
    const float* __restrict__ Wv,  const float* __restrict__ bv,
    const float* __restrict__ Wg,  const float* __restrict__ bg,
    const float* __restrict__ Wf1, const float* __restrict__ bf1,
    const float* __restrict__ Wf2, const float* __restrict__ bf2,
    const float* __restrict__ Wf3, const float* __restrict__ bf3,
    const float* __restrict__ Wih, const float* __restrict__ bih,
    const float* __restrict__ Whh, const float* __restrict__ bhh,
    float* __restrict__ out)          // [12,B]
{
    __shared__ __align__(16) f16 x16[2][16][72];   // 2 x 2304 B
    __shared__ __align__(16) f16 z1b[2][16][32];   // 2 x 1024 B

    const int l = threadIdx.x;
    const int r = l & 15, g = l >> 4;        // A-row / D-col = r; k-block & D-row-group = g
    const int bw = blockIdx.x * 32;          // wave's first global batch row
    const f32x4 kz = {0.f, 0.f, 0.f, 0.f};

#define XB(tt) ((char*)x16 + (tt) * 2304)
#define ZB(tt) ((char*)z1b + (tt) * 1024)

    // ---- zero LDS
    #pragma unroll
    for (int d = 0; d < 18; ++d) ((unsigned*)x16)[d * 64 + l] = 0u;
    #pragma unroll
    for (int d = 0; d < 8; ++d)  ((unsigned*)z1b)[d * 64 + l] = 0u;

    // ---- phase 1: es for 32 rows -> x16 rows (read premeaned, or cold fallback)
    if (esrc) {
        const float4* s4 = (const float4*)esrc;
        #pragma unroll
        for (int tt = 0; tt < 2; ++tt) {
            const size_t base = (size_t)(bw + tt * 16) * 15;
            #pragma unroll
            for (int s = 0; s < 4; ++s) {
                const int u = s * 64 + l;                 // 240 units per tile
                if (s < 3 || l < 48) {
                    const float4 v = s4[base + u];
                    const int row = u / 15, q4 = u - row * 15;
                    f16x4 h = {(f16)v.x, (f16)v.y, (f16)v.z, (f16)v.w};
                    *(f16x4*)&x16[tt][row][q4 * 4] = h;
                }
            }
        }
    } else {   // cold correctness path: serial scan (ws too small)
        const float4* e4 = (const float4*)enc;
        const float s = 1.f / 48.f;
        for (int tt = 0; tt < 2; ++tt) {
            const size_t base = (size_t)(bw + tt * 16) * 15;
            #pragma unroll 1
            for (int s0 = 0; s0 < 4; ++s0) {
                const int u = s0 * 64 + l;
                if (u < 240) {
                    float ax = 0.f, ay = 0.f, az = 0.f, aw = 0.f;
                    for (int L = 0; L < 48; ++L) {
                        const float4 v = e4[(size_t)L * (NB * 15) + base + u];
                        ax += v.x; ay += v.y; az += v.z; aw += v.w;
                    }
                    const int row = u / 15, q4 = u - row * 15;
                    f16x4 h = {(f16)(ax*s), (f16)(ay*s), (f16)(az*s), (f16)(aw*s)};
                    *(f16x4*)&x16[tt][row][q4 * 4] = h;
                }
            }
        }
    }

    // ---- load weight B-fragments (f16, persistent in VGPRs, shared by tiles)
    // B-frag element e of lane l = W[k = kt*32 + g*8 + e][n = nt*16 + r]
    f16x8 lf[2][8];                  // LSTM; t = gate*2 + jh; k: 0..33 Wih, 34..63 Whh
    #pragma unroll
    for (int kt = 0; kt < 2; ++kt)
        #pragma unroll
        for (int t = 0; t < 8; ++t) {
            const int gate = t >> 1, j = (t & 1) * 16 + r;
            const int trow = gate * 30 + j;
            f16x8 w;
            #pragma unroll
            for (int e = 0; e < 8; ++e) {
                const int k = kt * 32 + g * 8 + e;
                float val = 0.f;
                if (j < 30) val = (k < 34) ? Wih[trow * 34 + k] : Whh[trow * 30 + (k - 34)];
                w[e] = (f16)val;
            }
            lf[kt][t] = w;
        }
    f16x8 gf[2][2];                  // gate; kt0 over x16 cols 32..63 (kl>=2 -> h), kt1 over V
    #pragma unroll
    for (int nt = 0; nt < 2; ++nt) {
        const int j = nt * 16 + r;
        f16x8 w0, w1;
        #pragma unroll
        for (int e = 0; e < 8; ++e) {
            const int kl = g * 8 + e;
            w0[e] = (f16)((j < 30 && kl >= 2) ? Wg[j * 60 + (kl - 2)] : 0.f);
            w1[e] = (f16)((j < 30 && kl < 30) ? Wg[j * 60 + 30 + kl] : 0.f);
        }
        gf[0][nt] = w0; gf[1][nt] = w1;
    }
    f16x8 f1f[2];                    // fc1 over x16 cols 32..63 (kl>=2 -> h_new); se via bias
    #pragma unroll
    for (int nt = 0; nt < 2; ++nt) {
        const int j = nt * 16 + r;
        f16x8 w;
        #pragma unroll
        for (int e = 0; e < 8; ++e) {
            const int kl = g * 8 + e;
            w[e] = (f16)((j < 30 && kl >= 2) ? Wf1[j * 31 + (kl - 2)] : 0.f);
        }
        f1f[nt] = w;
    }
    f16x8 f2f;                       // fc2: z1(30) -> 15
    #pragma unroll
    for (int e = 0; e < 8; ++e) {
        const int kl = g * 8 + e;
        f2f[e] = (f16)((r < 15 && kl < 30) ? Wf2[r * 30 + kl] : 0.f);
    }
    f16x8 f3f;                       // fc3: z2(15) -> 1 (col 0 only)
    #pragma unroll
    for (int e = 0; e < 8; ++e) {
        const int kl = g * 8 + e;
        f3f[e] = (f16)((r == 0 && kl < 15) ? Wf3[kl] : 0.f);
    }
    f16x8 vf[2][2];                  // Wv: es(60) -> 30
    #pragma unroll
    for (int kt = 0; kt < 2; ++kt)
        #pragma unroll
        for (int nt = 0; nt < 2; ++nt) {
            const int j = nt * 16 + r;
            f16x8 w;
            #pragma unroll
            for (int e = 0; e < 8; ++e) {
                const int kl = kt * 32 + g * 8 + e;
                w[e] = (f16)((j < 30 && kl < 60) ? Wv[j * 60 + kl] : 0.f);
            }
            vf[kt][nt] = w;
        }

    // ---- biases (D-layout: depend on lane's col only; shared by tiles)
    float bl[8], bgv[2], bf1v[2], wf1se[2];
    #pragma unroll
    for (int t = 0; t < 8; ++t) {
        const int gate = t >> 1, j = (t & 1) * 16 + r;
        bl[t] = (j < 30) ? bih[gate * 30 + j] + bhh[gate * 30 + j] : 0.f;
    }
    #pragma unroll
    for (int nt = 0; nt < 2; ++nt) {
        const int j = nt * 16 + r;
        bgv[nt]   = (j < 30) ? bg[j]  : 0.f;
        bf1v[nt]  = (j < 30) ? bf1[j] : 0.f;
        wf1se[nt] = (j < 30) ? Wf1[j * 31 + 30] : 0.f;
    }
    const float bf2v = (r < 15) ? bf2[r] : 0.f;
    const float bf3v = bf3[0];
    const float bv0  = bv[r];
    const float bv1  = (16 + r < 30) ? bv[16 + r] : 0.f;

    // ---- V = es @ Wv.T + bv per tile (softmax over singleton axis == 1)
    float VD[2][2][4];
    #pragma unroll
    for (int tt = 0; tt < 2; ++tt) {
        const f16x8 ea0 = *(const f16x8*)(XB(tt) + (size_t)r * 144 + g * 16);
        const f16x8 ea1 = *(const f16x8*)(XB(tt) + (size_t)r * 144 + 64 + g * 16);
        f32x4 vd0 = MFMA16(ea0, vf[0][0], kz); vd0 = MFMA16(ea1, vf[1][0], vd0);
        f32x4 vd1 = MFMA16(ea0, vf[0][1], kz); vd1 = MFMA16(ea1, vf[1][1], vd1);
        #pragma unroll
        for (int q = 0; q < 4; ++q) { VD[tt][0][q] = vd0[q] + bv0; VD[tt][1][q] = vd1[q] + bv1; }
        #pragma unroll
        for (int nt = 0; nt < 2; ++nt)
            #pragma unroll
            for (int q = 0; q < 4; ++q)
                z1b[tt][4 * g + q][nt * 16 + r] = (f16)VD[tt][nt][q];   // stage V for A-frag
    }
    f16x8 va[2];
    #pragma unroll
    for (int tt = 0; tt < 2; ++tt)
        va[tt] = *(const f16x8*)(ZB(tt) + (size_t)r * 64 + g * 16);

    // ---- h0 (D-layout regs + x16 h-region), rin0
    float hD[2][2][4];
    #pragma unroll
    for (int tt = 0; tt < 2; ++tt)
        #pragma unroll
        for (int nt = 0; nt < 2; ++nt)
            #pragma unroll
            for (int q = 0; q < 4; ++q) {
                const int row = 4 * g + q, j = nt * 16 + r;
                hD[tt][nt][q] = (j < 30) ? hidden[(size_t)(bw + tt * 16 + row) * 30 + j] : 0.f;
                x16[tt][row][34 + nt * 16 + r] = (f16)hD[tt][nt][q];  // nt1 r>=14 -> scratch
            }
    if (l < 32) {    // rin0 = nan_to_num(y[:,0,:]); global row = bw + l
        const float* yp = y + (size_t)(bw + l) * 52;
        #pragma unroll
        for (int d = 0; d < 4; ++d) {
            float v = yp[d];
            x16[l >> 4][l & 15][d] = (f16)((v == v) ? v : 0.f);
        }
    }

    // ---- 12-step recurrence (wave-private; dual independent chains)
    float c[2][2][4] = {};
    #pragma unroll 1
    for (int i = 1; i <= 12; ++i) {
        const float se = (float)i * (1.f / 12.f);

        // A: gate = sig([h|V] @ Wg.T + bg); enh -> x16 cols 4..33
        // (cols 32,33 stale enh[28,29] are zero-weighted in gf[0])
        #pragma unroll
        for (int tt = 0; tt < 2; ++tt) {
            const f16x8 xhg = *(const f16x8*)(XB(tt) + (size_t)r * 144 + 64 + g * 16);
            f32x4 gd0 = MFMA16(xhg, gf[0][0], kz); gd0 = MFMA16(va[tt], gf[1][0], gd0);
            f32x4 gd1 = MFMA16(xhg, gf[0][1], kz); gd1 = MFMA16(va[tt], gf[1][1], gd1);
            #pragma unroll
            for (int nt = 0; nt < 2; ++nt)
                #pragma unroll
                for (int q = 0; q < 4; ++q) {
                    const float a  = (nt ? gd1[q] : gd0[q]) + bgv[nt];
                    const float gt = fast_sig(a);
                    const float enh = gt * hD[tt][nt][q] + (1.f - gt) * VD[tt][nt][q];
                    const int j = nt * 16 + r;
                    if (j < 30) x16[tt][4 * g + q][4 + j] = (f16)enh;
                }
        }
        __builtin_amdgcn_wave_barrier();

        // B: LSTM. A-tiles reloaded AFTER A's enh stores (r5 bug lesson).
        #pragma unroll
        for (int tt = 0; tt < 2; ++tt) {
            const f16x8 xa0 = *(const f16x8*)(XB(tt) + (size_t)r * 144 + g * 16);
            const f16x8 xa1 = *(const f16x8*)(XB(tt) + (size_t)r * 144 + 64 + g * 16);
            f32x4 ld[8];
            #pragma unroll
            for (int t = 0; t < 8; ++t) {
                ld[t] = MFMA16(xa0, lf[0][t], kz);
                ld[t] = MFMA16(xa1, lf[1][t], ld[t]);
            }
            #pragma unroll
            for (int jh = 0; jh < 2; ++jh)
                #pragma unroll
                for (int q = 0; q < 4; ++q) {
                    const float ii = fast_sig (ld[0 + jh][q] + bl[0 + jh]);
                    const float ff = fast_sig (ld[2 + jh][q] + bl[2 + jh]);
                    const float gg = fast_tanh(ld[4 + jh][q] + bl[4 + jh]);
                    const float oo = fast_sig (ld[6 + jh][q] + bl[6 + jh]);
                    const float cn = ff * c[tt][jh][q] + ii * gg;
                    c[tt][jh][q] = cn;
                    const float hn = oo * fast_tanh(cn);
                    hD[tt][jh][q] = hn;
                    x16[tt][4 * g + q][34 + jh * 16 + r] = (f16)hn;   // jh1 r>=14 -> scratch
                }
        }
        __builtin_amdgcn_wave_barrier();

        // prefetch next rin's y components (consumed in E)
        float py1 = 0, py2 = 0, py3 = 0;
        if (l < 32) {
            const float* yp = y + (size_t)(bw + l) * 52 + (size_t)i * 4;
            py1 = yp[1]; py2 = yp[2]; py3 = yp[3];
        }

        // C: z1 = relu([h_new|se] @ Wf1.T + bf1)  (se folded into dynamic bias)
        #pragma unroll
        for (int tt = 0; tt < 2; ++tt) {
            const f16x8 hn = *(const f16x8*)(XB(tt) + (size_t)r * 144 + 64 + g * 16);
            f32x4 d0 = MFMA16(hn, f1f[0], kz);
            f32x4 d1 = MFMA16(hn, f1f[1], kz);
            #pragma unroll
            for (int nt = 0; nt < 2; ++nt)
                #pragma unroll
                for (int q = 0; q < 4; ++q) {
                    const float z = fmaxf((nt ? d1[q] : d0[q]) + bf1v[nt] + se * wf1se[nt], 0.f);
                    z1b[tt][4 * g + q][nt * 16 + r] = (f16)z;
                }
        }
        __builtin_amdgcn_wave_barrier();

        // D: z2 = relu(z1 @ Wf2.T + bf2) -> z1b cols 0..15
        #pragma unroll
        for (int tt = 0; tt < 2; ++tt) {
            const f16x8 z1a = *(const f16x8*)(ZB(tt) + (size_t)r * 64 + g * 16);
            f32x4 d = MFMA16(z1a, f2f, kz);
            #pragma unroll
            for (int q = 0; q < 4; ++q)
                z1b[tt][4 * g + q][r] = (f16)fmaxf(d[q] + bf2v, 0.f);
        }
        __builtin_amdgcn_wave_barrier();

        // E: out = z2 @ Wf3.T + bf3 (stale z1 cols 16..31 killed by zero weights)
        #pragma unroll
        for (int tt = 0; tt < 2; ++tt) {
            const f16x8 z2a = *(const f16x8*)(ZB(tt) + (size_t)r * 64 + g * 16);
            f32x4 od = MFMA16(z2a, f3f, kz);
            if (r == 0) {
                #pragma unroll
                for (int q = 0; q < 4; ++q) {
                    const float o = od[q] + bf3v;
                    out[(size_t)(i - 1) * NB + bw + tt * 16 + 4 * g + q] = o;
                    x16[tt][4 * g + q][3] = (f16)o;       // rin[3] = out
                }
            }
        }
        if (l < 32) {                                      // rin[0..2] = y[:, i, 1:4]
            x16[l >> 4][l & 15][0] = (f16)py1;
            x16[l >> 4][l & 15][1] = (f16)py2;
            x16[l >> 4][l & 15][2] = (f16)py3;
        }
        __builtin_amdgcn_wave_barrier();
    }
#undef XB
#undef ZB
}

extern "C" void kernel_launch(void* const* d_in, const int* in_sizes, int n_in,
                              void* d_out, int out_size, void* d_ws, size_t ws_size,
                              hipStream_t stream) {
    (void)in_sizes; (void)n_in; (void)out_size;
    // 0 batch_ids, 1 y, 2 encoder_outputs, 3 hidden, 4 Wq, 5 bq, 6 Wk, 7 bk,
    // 8 Wv, 9 bv, 10 Wsa1, 11 bsa1, 12 Wsa2, 13 bsa2, 14 Wg, 15 bg,
    // 16 Wf1, 17 bf1, 18 Wf2, 19 bf2, 20 Wf3, 21 bf3, 22 W_ih, 23 b_ih,
    // 24 W_hh, 25 b_hh.  (Wq/bq/Wk/bk/Wsa* dead: softmax over size-1 axis == 1)
    const float* enc = (const float*)d_in[2];
    const size_t es_bytes = (size_t)NB * 60 * sizeof(float);
    float* es = (ws_size >= es_bytes) ? (float*)d_ws : nullptr;

    if (es) {
        // DIAGNOSTIC: es_kernel launched TWICE (idempotent — same deterministic
        // write to the same ws region). dur_total − 91.4us(r8) = es duration,
        // decoder = 91.4 − es. Decoder below is byte-identical to r8.
        es_kernel<<<dim3(NB * 15 / 256), dim3(256), 0, stream>>>(enc, es);
        es_kernel<<<dim3(NB * 15 / 256), dim3(256), 0, stream>>>(enc, es);
    }
    decoder_kernel<<<dim3(NB / 32), dim3(64), 0, stream>>>(
        (const float*)d_in[1],  enc, es, (const float*)d_in[3],
        (const float*)d_in[8],  (const float*)d_in[9],
        (const float*)d_in[14], (const float*)d_in[15],
        (const float*)d_in[16], (const float*)d_in[17],
        (const float*)d_in[18], (const float*)d_in[19],
        (const float*)d_in[20], (const float*)d_in[21],
        (const float*)d_in[22], (const float*)d_in[23],
        (const float*)d_in[24], (const float*)d_in[25],
        (float*)d_out);
}

// Round 12
// 78.370 us; speedup vs baseline: 1.5506x; 1.5506x over previous
//
#include <hip/hip_runtime.h>
#include <math.h>

#define NB 16384
typedef _Float16 f16;
typedef _Float16 f16x8 __attribute__((ext_vector_type(8)));
typedef _Float16 f16x4 __attribute__((ext_vector_type(4)));
typedef float f32x4 __attribute__((ext_vector_type(4)));

__device__ __forceinline__ float fast_sig(float v)  { return __builtin_amdgcn_rcpf(1.0f + __expf(-v)); }
__device__ __forceinline__ float fast_tanh(float v) { return 1.0f - 2.0f * __builtin_amdgcn_rcpf(1.0f + __expf(2.0f * v)); }

#define MFMA16(A, B, C) __builtin_amdgcn_mfma_f32_16x16x32_f16(A, B, C, 0, 0, 0)
#define WBAR() __builtin_amdgcn_wave_barrier()

// ---------------- kernel 1: es = mean_L(enc) — measured 30us ≈ BW roofline ------
__global__ __launch_bounds__(256) void es_kernel(
    const float* __restrict__ enc, float* __restrict__ es)
{
    const int u = blockIdx.x * 256 + threadIdx.x;    // float4 unit
    const float4* e4 = (const float4*)enc;
    float ax = 0.f, ay = 0.f, az = 0.f, aw = 0.f;
    #pragma unroll 8
    for (int L = 0; L < 48; ++L) {
        const float4 v = e4[(size_t)L * (NB * 15) + u];
        ax += v.x; ay += v.y; az += v.z; aw += v.w;
    }
    const float s = 1.f / 48.f;
    float4 r; r.x = ax * s; r.y = ay * s; r.z = az * s; r.w = aw * s;
    ((float4*)es)[u] = r;
}

// ---------------- kernel 2: decode — 2-wave spine/head pipeline -----------------
// 512 blocks x 128 thr (2 waves), 32 rows (2 full 16-row tiles) per block.
// wave0 "spine": A_i (gate) ; B_i (LSTM).  wave1 "head": C/D/E of step i-1,
// overlapped with A_i.  r11 bug fixed: the x16 es region (cols 0..3 rin, cols
// 34..63 h) is overwritten ONLY AFTER the V MFMA has consumed es (extra barrier).
// x16 row layout (72 halves): [0..3]=rin [4..33]=enh [34..63]=h [64..71]=scratch
__global__ __launch_bounds__(128, 1) void decoder_kernel(
    const float* __restrict__ y,      // [B,13,4]
    const float* __restrict__ enc,    // [48,B,60]
    const float* __restrict__ esrc,   // [B,60] premeaned (or null -> cold scan)
    const float* __restrict__ hidden, // [B,30]
    const float* __restrict__ Wv,  const float* __restrict__ bv,
    const float* __restrict__ Wg,  const float* __restrict__ bg,
    const float* __restrict__ Wf1, const float* __restrict__ bf1,
    const float* __restrict__ Wf2, const float* __restrict__ bf2,
    const float* __restrict__ Wf3, const float* __restrict__ bf3,
    const float* __restrict__ Wih, const float* __restrict__ bih,
    const float* __restrict__ Whh, const float* __restrict__ bhh,
    float* __restrict__ out)          // [12,B]
{
    __shared__ __align__(16) f16 x16[2][16][72];   // 2 x 2304 B
    __shared__ __align__(16) f16 z1b[2][16][32];   // 2 x 1024 B

    const int t = threadIdx.x;
    const int wid = t >> 6, l = t & 63;
    const int r = l & 15, g = l >> 4;        // A-row / D-col = r; k-block & D-row-group = g
    const int bw = blockIdx.x * 32;          // block's first global batch row
    const f32x4 kz = {0.f, 0.f, 0.f, 0.f};

#define XB(tt) ((char*)x16 + (tt) * 2304)
#define ZB(tt) ((char*)z1b + (tt) * 1024)

    // ---- zero LDS (128 threads)
    #pragma unroll
    for (int d = 0; d < 9; ++d) ((unsigned*)x16)[d * 128 + t] = 0u;
    #pragma unroll
    for (int d = 0; d < 4; ++d) ((unsigned*)z1b)[d * 128 + t] = 0u;

    // ---- stage es for 32 rows -> x16 (premeaned fast path, or cold scan)
    if (esrc) {
        const float4* s4 = (const float4*)esrc + (size_t)bw * 15;
        #pragma unroll
        for (int s = 0; s < 4; ++s) {
            const int u = s * 128 + t;               // 480 float4 units
            if (u < 480) {
                const float4 v = s4[u];
                const int tile = u / 240, uu = u - tile * 240;
                const int row = uu / 15, q4 = uu - row * 15;
                f16x4 h = {(f16)v.x, (f16)v.y, (f16)v.z, (f16)v.w};
                *(f16x4*)&x16[tile][row][q4 * 4] = h;
            }
        }
    } else {   // cold correctness path (ws too small)
        const float4* e4 = (const float4*)enc + (size_t)bw * 15;
        const float sc = 1.f / 48.f;
        #pragma unroll 1
        for (int s = 0; s < 4; ++s) {
            const int u = s * 128 + t;
            if (u < 480) {
                const int tile = u / 240, uu = u - tile * 240;
                const int row = uu / 15, q4 = uu - row * 15;
                float ax = 0.f, ay = 0.f, az = 0.f, aw = 0.f;
                for (int L = 0; L < 48; ++L) {
                    const float4 v = e4[(size_t)L * (NB * 15) + uu + tile * 240];
                    ax += v.x; ay += v.y; az += v.z; aw += v.w;
                }
                f16x4 h = {(f16)(ax*sc), (f16)(ay*sc), (f16)(az*sc), (f16)(aw*sc)};
                *(f16x4*)&x16[tile][row][q4 * 4] = h;
            }
        }
    }

    // ---- per-wave weight fragments (B-frag elem e of lane l = W[kt*32+g*8+e][nt*16+r])
    f16x8 lf[2][8], gf[2][2], vf[2][2], f1f[2], f2f, f3f;
    float bl[8], bgv[2], bv0 = 0.f, bv1 = 0.f, bf1v[2], wf1se[2], bf2v = 0.f, bf3v = 0.f;
    float hD[2][2][4], VD[2][2][4], c[2][2][4] = {};
    float r0v[4] = {0.f, 0.f, 0.f, 0.f};     // head: rin0 staged in REGISTERS

    if (wid == 0) {      // spine: LSTM + gate + Wv weights; h0 -> REGISTERS only
        #pragma unroll
        for (int kt = 0; kt < 2; ++kt)
            #pragma unroll
            for (int tq = 0; tq < 8; ++tq) {
                const int gate = tq >> 1, j = (tq & 1) * 16 + r;
                const int trow = gate * 30 + j;
                f16x8 w;
                #pragma unroll
                for (int e = 0; e < 8; ++e) {
                    const int k = kt * 32 + g * 8 + e;
                    float val = 0.f;
                    if (j < 30) val = (k < 34) ? Wih[trow * 34 + k] : Whh[trow * 30 + (k - 34)];
                    w[e] = (f16)val;
                }
                lf[kt][tq] = w;
            }
        #pragma unroll
        for (int nt = 0; nt < 2; ++nt) {
            const int j = nt * 16 + r;
            f16x8 w0, w1;
            #pragma unroll
            for (int e = 0; e < 8; ++e) {
                const int kl = g * 8 + e;
                w0[e] = (f16)((j < 30 && kl >= 2) ? Wg[j * 60 + (kl - 2)] : 0.f);
                w1[e] = (f16)((j < 30 && kl < 30) ? Wg[j * 60 + 30 + kl] : 0.f);
            }
            gf[0][nt] = w0; gf[1][nt] = w1;
        }
        #pragma unroll
        for (int kt = 0; kt < 2; ++kt)
            #pragma unroll
            for (int nt = 0; nt < 2; ++nt) {
                const int j = nt * 16 + r;
                f16x8 w;
                #pragma unroll
                for (int e = 0; e < 8; ++e) {
                    const int kl = kt * 32 + g * 8 + e;
                    w[e] = (f16)((j < 30 && kl < 60) ? Wv[j * 60 + kl] : 0.f);
                }
                vf[kt][nt] = w;
            }
        #pragma unroll
        for (int tq = 0; tq < 8; ++tq) {
            const int gate = tq >> 1, j = (tq & 1) * 16 + r;
            bl[tq] = (j < 30) ? bih[gate * 30 + j] + bhh[gate * 30 + j] : 0.f;
        }
        #pragma unroll
        for (int nt = 0; nt < 2; ++nt) {
            const int j = nt * 16 + r;
            bgv[nt] = (j < 30) ? bg[j] : 0.f;
        }
        bv0 = bv[r];
        bv1 = (16 + r < 30) ? bv[16 + r] : 0.f;
        #pragma unroll
        for (int tt = 0; tt < 2; ++tt)       // h0 -> registers (x16 write deferred!)
            #pragma unroll
            for (int nt = 0; nt < 2; ++nt)
                #pragma unroll
                for (int q = 0; q < 4; ++q) {
                    const int row = 4 * g + q, j = nt * 16 + r;
                    hD[tt][nt][q] = (j < 30) ? hidden[(size_t)(bw + tt * 16 + row) * 30 + j] : 0.f;
                }
    } else {             // head: fc weights; rin0 -> registers (x16 write deferred!)
        #pragma unroll
        for (int nt = 0; nt < 2; ++nt) {
            const int j = nt * 16 + r;
            f16x8 w;
            #pragma unroll
            for (int e = 0; e < 8; ++e) {
                const int kl = g * 8 + e;
                w[e] = (f16)((j < 30 && kl >= 2) ? Wf1[j * 31 + (kl - 2)] : 0.f);
            }
            f1f[nt] = w;
            bf1v[nt]  = (j < 30) ? bf1[j] : 0.f;
            wf1se[nt] = (j < 30) ? Wf1[j * 31 + 30] : 0.f;
        }
        #pragma unroll
        for (int e = 0; e < 8; ++e) {
            const int kl = g * 8 + e;
            f2f[e] = (f16)((r < 15 && kl < 30) ? Wf2[r * 30 + kl] : 0.f);
            f3f[e] = (f16)((r == 0 && kl < 15) ? Wf3[kl] : 0.f);
        }
        bf2v = (r < 15) ? bf2[r] : 0.f;
        bf3v = bf3[0];
        if (l < 32) {    // rin0 = nan_to_num(y[:,0,:]) -> registers
            const float* yp = y + (size_t)(bw + l) * 52;
            #pragma unroll
            for (int d = 0; d < 4; ++d) {
                float v = yp[d];
                r0v[d] = (v == v) ? v : 0.f;
            }
        }
    }
    __syncthreads();     // es fully staged & visible

    // ---- V = es @ Wv.T + bv (spine; reads x16 es cols 0..63 — MUST precede
    //      any overwrite of the es region).  Softmax over singleton axis == 1.
    f16x8 va[2];
    if (wid == 0) {
        #pragma unroll
        for (int tt = 0; tt < 2; ++tt) {
            const f16x8 ea0 = *(const f16x8*)(XB(tt) + (size_t)r * 144 + g * 16);
            const f16x8 ea1 = *(const f16x8*)(XB(tt) + (size_t)r * 144 + 64 + g * 16);
            f32x4 vd0 = MFMA16(ea0, vf[0][0], kz); vd0 = MFMA16(ea1, vf[1][0], vd0);
            f32x4 vd1 = MFMA16(ea0, vf[0][1], kz); vd1 = MFMA16(ea1, vf[1][1], vd1);
            #pragma unroll
            for (int q = 0; q < 4; ++q) { VD[tt][0][q] = vd0[q] + bv0; VD[tt][1][q] = vd1[q] + bv1; }
            #pragma unroll
            for (int nt = 0; nt < 2; ++nt)
                #pragma unroll
                for (int q = 0; q < 4; ++q)
                    z1b[tt][4 * g + q][nt * 16 + r] = (f16)VD[tt][nt][q];
        }
        WBAR();
        #pragma unroll
        for (int tt = 0; tt < 2; ++tt)
            va[tt] = *(const f16x8*)(ZB(tt) + (size_t)r * 64 + g * 16);
    }
    __syncthreads();     // r11 FIX: es reads drained -> es region may be reused

    // ---- NOW overwrite the es region: h0 (spine, cols 34..63), rin0 (head, 0..3)
    if (wid == 0) {
        #pragma unroll
        for (int tt = 0; tt < 2; ++tt)
            #pragma unroll
            for (int nt = 0; nt < 2; ++nt)
                #pragma unroll
                for (int q = 0; q < 4; ++q)
                    x16[tt][4 * g + q][34 + nt * 16 + r] = (f16)hD[tt][nt][q];  // nt1 r>=14 -> scratch
    } else {
        if (l < 32) {
            #pragma unroll
            for (int d = 0; d < 4; ++d)
                x16[l >> 4][l & 15][d] = (f16)r0v[d];
        }
    }
    // spine's A_1 reads its own h0 writes (same-wave order); head's rin0 is
    // consumed by B_1 only after the P1-end __syncthreads -> no barrier needed.

    // ---- 12-step pipelined recurrence ------------------------------------------
    float py1 = 0.f, py2 = 0.f, py3 = 0.f;   // head's y prefetch
    #pragma unroll 1
    for (int i = 1; i <= 12; ++i) {
        // P1: spine A_i  ||  head C/D/E of step i-1
        if (wid == 0) {
            // A: gate = sig([h|V] @ Wg.T + bg); enh -> x16 cols 4..33
            // (cols 32,33 stale values are zero-weighted in gf[0])
            #pragma unroll
            for (int tt = 0; tt < 2; ++tt) {
                const f16x8 xhg = *(const f16x8*)(XB(tt) + (size_t)r * 144 + 64 + g * 16);
                f32x4 gd0 = MFMA16(xhg, gf[0][0], kz); gd0 = MFMA16(va[tt], gf[1][0], gd0);
                f32x4 gd1 = MFMA16(xhg, gf[0][1], kz); gd1 = MFMA16(va[tt], gf[1][1], gd1);
                #pragma unroll
                for (int nt = 0; nt < 2; ++nt)
                    #pragma unroll
                    for (int q = 0; q < 4; ++q) {
                        const float a  = (nt ? gd1[q] : gd0[q]) + bgv[nt];
                        const float gt = fast_sig(a);
                        const float enh = gt * hD[tt][nt][q] + (1.f - gt) * VD[tt][nt][q];
                        const int j = nt * 16 + r;
                        if (j < 30) x16[tt][4 * g + q][4 + j] = (f16)enh;
                    }
            }
        } else if (i > 1) {
            const int s = i - 1;
            const float se = (float)s * (1.f / 12.f);
            // C: z1 = relu([h_s|se] @ Wf1.T + bf1)  (concurrent cols 32/33 writes
            // by spine A are finite f16 and zero-weighted in f1f -> safe)
            #pragma unroll
            for (int tt = 0; tt < 2; ++tt) {
                const f16x8 hn = *(const f16x8*)(XB(tt) + (size_t)r * 144 + 64 + g * 16);
                f32x4 d0 = MFMA16(hn, f1f[0], kz);
                f32x4 d1 = MFMA16(hn, f1f[1], kz);
                #pragma unroll
                for (int nt = 0; nt < 2; ++nt)
                    #pragma unroll
                    for (int q = 0; q < 4; ++q) {
                        const float z = fmaxf((nt ? d1[q] : d0[q]) + bf1v[nt] + se * wf1se[nt], 0.f);
                        z1b[tt][4 * g + q][nt * 16 + r] = (f16)z;
                    }
            }
            WBAR();
            // D: z2 = relu(z1 @ Wf2.T + bf2) -> z1b cols 0..15
            #pragma unroll
            for (int tt = 0; tt < 2; ++tt) {
                const f16x8 z1a = *(const f16x8*)(ZB(tt) + (size_t)r * 64 + g * 16);
                f32x4 d = MFMA16(z1a, f2f, kz);
                #pragma unroll
                for (int q = 0; q < 4; ++q)
                    z1b[tt][4 * g + q][r] = (f16)fmaxf(d[q] + bf2v, 0.f);
            }
            WBAR();
            // E: out_s = z2 @ Wf3.T + bf3; rin_{s+1} = [y[:,s,1:4], out_s]
            #pragma unroll
            for (int tt = 0; tt < 2; ++tt) {
                const f16x8 z2a = *(const f16x8*)(ZB(tt) + (size_t)r * 64 + g * 16);
                f32x4 od = MFMA16(z2a, f3f, kz);
                if (r == 0) {
                    #pragma unroll
                    for (int q = 0; q < 4; ++q) {
                        const float o = od[q] + bf3v;
                        out[(size_t)(s - 1) * NB + bw + tt * 16 + 4 * g + q] = o;
                        x16[tt][4 * g + q][3] = (f16)o;
                    }
                }
            }
            if (l < 32) {
                x16[l >> 4][l & 15][0] = (f16)py1;
                x16[l >> 4][l & 15][1] = (f16)py2;
                x16[l >> 4][l & 15][2] = (f16)py3;
            }
        }
        __syncthreads();   // h_{i-1}+enh_i+rin_i all settled for B_i

        // P2: spine B_i  ||  head y-prefetch for step i
        if (wid == 0) {
            #pragma unroll
            for (int tt = 0; tt < 2; ++tt) {
                const f16x8 xa0 = *(const f16x8*)(XB(tt) + (size_t)r * 144 + g * 16);
                const f16x8 xa1 = *(const f16x8*)(XB(tt) + (size_t)r * 144 + 64 + g * 16);
                f32x4 ld[8];
                #pragma unroll
                for (int tq = 0; tq < 8; ++tq) {
                    ld[tq] = MFMA16(xa0, lf[0][tq], kz);
                    ld[tq] = MFMA16(xa1, lf[1][tq], ld[tq]);
                }
                #pragma unroll
                for (int jh = 0; jh < 2; ++jh)
                    #pragma unroll
                    for (int q = 0; q < 4; ++q) {
                        const float ii = fast_sig (ld[0 + jh][q] + bl[0 + jh]);
                        const float ff = fast_sig (ld[2 + jh][q] + bl[2 + jh]);
                        const float gg = fast_tanh(ld[4 + jh][q] + bl[4 + jh]);
                        const float oo = fast_sig (ld[6 + jh][q] + bl[6 + jh]);
                        const float cn = ff * c[tt][jh][q] + ii * gg;
                        c[tt][jh][q] = cn;
                        const float hn = oo * fast_tanh(cn);
                        hD[tt][jh][q] = hn;
                        x16[tt][4 * g + q][34 + jh * 16 + r] = (f16)hn;  // jh1 r>=14 -> scratch
                    }
            }
        } else {
            if (l < 32) {
                const float* yp = y + (size_t)(bw + l) * 52 + (size_t)i * 4;
                py1 = yp[1]; py2 = yp[2]; py3 = yp[3];
            }
        }
        __syncthreads();   // h_i visible for head's CDE_i and spine's A_{i+1}
    }

    // ---- epilogue: head finishes C/D/E of step 12
    if (wid == 1) {
        const int s = 12;
        const float se = 1.0f;
        #pragma unroll
        for (int tt = 0; tt < 2; ++tt) {
            const f16x8 hn = *(const f16x8*)(XB(tt) + (size_t)r * 144 + 64 + g * 16);
            f32x4 d0 = MFMA16(hn, f1f[0], kz);
            f32x4 d1 = MFMA16(hn, f1f[1], kz);
            #pragma unroll
            for (int nt = 0; nt < 2; ++nt)
                #pragma unroll
                for (int q = 0; q < 4; ++q) {
                    const float z = fmaxf((nt ? d1[q] : d0[q]) + bf1v[nt] + se * wf1se[nt], 0.f);
                    z1b[tt][4 * g + q][nt * 16 + r] = (f16)z;
                }
        }
        WBAR();
        #pragma unroll
        for (int tt = 0; tt < 2; ++tt) {
            const f16x8 z1a = *(const f16x8*)(ZB(tt) + (size_t)r * 64 + g * 16);
            f32x4 d = MFMA16(z1a, f2f, kz);
            #pragma unroll
            for (int q = 0; q < 4; ++q)
                z1b[tt][4 * g + q][r] = (f16)fmaxf(d[q] + bf2v, 0.f);
        }
        WBAR();
        #pragma unroll
        for (int tt = 0; tt < 2; ++tt) {
            const f16x8 z2a = *(const f16x8*)(ZB(tt) + (size_t)r * 64 + g * 16);
            f32x4 od = MFMA16(z2a, f3f, kz);
            if (r == 0) {
                #pragma unroll
                for (int q = 0; q < 4; ++q)
                    out[(size_t)(s - 1) * NB + bw + tt * 16 + 4 * g + q] = od[q] + bf3v;
            }
        }
    }
#undef XB
#undef ZB
}

extern "C" void kernel_launch(void* const* d_in, const int* in_sizes, int n_in,
                              void* d_out, int out_size, void* d_ws, size_t ws_size,
                              hipStream_t stream) {
    (void)in_sizes; (void)n_in; (void)out_size;
    // 0 batch_ids, 1 y, 2 encoder_outputs, 3 hidden, 4 Wq, 5 bq, 6 Wk, 7 bk,
    // 8 Wv, 9 bv, 10 Wsa1, 11 bsa1, 12 Wsa2, 13 bsa2, 14 Wg, 15 bg,
    // 16 Wf1, 17 bf1, 18 Wf2, 19 bf2, 20 Wf3, 21 bf3, 22 W_ih, 23 b_ih,
    // 24 W_hh, 25 b_hh.  (Wq/bq/Wk/bk/Wsa* dead: softmax over size-1 axis == 1)
    const float* enc = (const float*)d_in[2];
    const size_t es_bytes = (size_t)NB * 60 * sizeof(float);
    float* es = (ws_size >= es_bytes) ? (float*)d_ws : nullptr;

    if (es) {
        es_kernel<<<dim3(NB * 15 / 256), dim3(256), 0, stream>>>(enc, es);
    }
    decoder_kernel<<<dim3(NB / 32), dim3(128), 0, stream>>>(
        (const float*)d_in[1],  enc, es, (const float*)d_in[3],
        (const float*)d_in[8],  (const float*)d_in[9],
        (const float*)d_in[14], (const float*)d_in[15],
        (const float*)d_in[16], (const float*)d_in[17],
        (const float*)d_in[18], (const float*)d_in[19],
        (const float*)d_in[20], (const float*)d_in[21],
        (const float*)d_in[22], (const float*)d_in[23],
        (const float*)d_in[24], (const float*)d_in[25],
        (float*)d_out);
}

// Round 13
// 67.326 us; speedup vs baseline: 1.8050x; 1.1640x over previous
//
#include <hip/hip_runtime.h>
#include <math.h>

#define NB 16384
typedef _Float16 f16;
typedef _Float16 f16x8 __attribute__((ext_vector_type(8)));
typedef _Float16 f16x4 __attribute__((ext_vector_type(4)));
typedef float f32x4 __attribute__((ext_vector_type(4)));

__device__ __forceinline__ float fast_sig(float v)  { return __builtin_amdgcn_rcpf(1.0f + __expf(-v)); }
__device__ __forceinline__ float fast_tanh(float v) { return 1.0f - 2.0f * __builtin_amdgcn_rcpf(1.0f + __expf(2.0f * v)); }

#define MFMA16(A, B, C) __builtin_amdgcn_mfma_f32_16x16x32_f16(A, B, C, 0, 0, 0)
#define WBAR() __builtin_amdgcn_wave_barrier()

// ---------------- kernel 1: es = mean_L(enc) — measured 30us ≈ BW roofline ------
__global__ __launch_bounds__(256) void es_kernel(
    const float* __restrict__ enc, float* __restrict__ es)
{
    const int u = blockIdx.x * 256 + threadIdx.x;    // float4 unit
    const float4* e4 = (const float4*)enc;
    float ax = 0.f, ay = 0.f, az = 0.f, aw = 0.f;
    #pragma unroll 8
    for (int L = 0; L < 48; ++L) {
        const float4 v = e4[(size_t)L * (NB * 15) + u];
        ax += v.x; ay += v.y; az += v.z; aw += v.w;
    }
    const float s = 1.f / 48.f;
    float4 r; r.x = ax * s; r.y = ay * s; r.z = az * s; r.w = aw * s;
    ((float4*)es)[u] = r;
}

// ---------------- kernel 2: decode — spine/head pipeline, 1 tile/block ----------
// 1024 blocks x 128 thr (2 waves), ONE 16-row tile per block -> 8 waves/CU =
// 2 phase-shifted spine/head pairs per SIMD hiding each other's stalls
// (r12 had 1 wave/SIMD: every lgkm/trans/barrier bubble fully exposed).
// wave0 "spine": A_i ; B_i.  wave1 "head": C/D/E of step i-1 (|| A_i).
// x16 row layout (72 halves): [0..3]=rin [4..33]=enh [34..63]=h [64..71]=scratch
__global__ __launch_bounds__(128, 2) void decoder_kernel(
    const float* __restrict__ y,      // [B,13,4]
    const float* __restrict__ enc,    // [48,B,60]
    const float* __restrict__ esrc,   // [B,60] premeaned (or null -> cold scan)
    const float* __restrict__ hidden, // [B,30]
    const float* __restrict__ Wv,  const float* __restrict__ bv,
    const float* __restrict__ Wg,  const float* __restrict__ bg,
    const float* __restrict__ Wf1, const float* __restrict__ bf1,
    const float* __restrict__ Wf2, const float* __restrict__ bf2,
    const float* __restrict__ Wf3, const float* __restrict__ bf3,
    const float* __restrict__ Wih, const float* __restrict__ bih,
    const float* __restrict__ Whh, const float* __restrict__ bhh,
    float* __restrict__ out)          // [12,B]
{
    __shared__ __align__(16) f16 x16[16][72];   // 2304 B
    __shared__ __align__(16) f16 z1b[16][32];   // 1024 B

    const int t = threadIdx.x;
    const int wid = t >> 6, l = t & 63;
    const int r = l & 15, g = l >> 4;        // A-row / D-col = r; k-block & D-row-group = g
    const int bw = blockIdx.x * 16;          // block's first global batch row
    const f32x4 kz = {0.f, 0.f, 0.f, 0.f};

    // ---- zero LDS (128 threads; x16 = 576 u32, z1b = 256 u32)
    #pragma unroll
    for (int d = 0; d < 5; ++d) { const int u = d * 128 + t; if (u < 576) ((unsigned*)x16)[u] = 0u; }
    #pragma unroll
    for (int d = 0; d < 2; ++d) ((unsigned*)z1b)[d * 128 + t] = 0u;

    // ---- stage es for 16 rows -> x16 (premeaned fast path, or cold scan)
    if (esrc) {
        const float4* s4 = (const float4*)esrc + (size_t)bw * 15;
        #pragma unroll
        for (int s = 0; s < 2; ++s) {
            const int u = s * 128 + t;               // 240 float4 units
            if (u < 240) {
                const float4 v = s4[u];
                const int row = u / 15, q4 = u - row * 15;
                f16x4 h = {(f16)v.x, (f16)v.y, (f16)v.z, (f16)v.w};
                *(f16x4*)&x16[row][q4 * 4] = h;
            }
        }
    } else {   // cold correctness path (ws too small)
        const float4* e4 = (const float4*)enc + (size_t)bw * 15;
        const float sc = 1.f / 48.f;
        #pragma unroll 1
        for (int s = 0; s < 2; ++s) {
            const int u = s * 128 + t;
            if (u < 240) {
                const int row = u / 15, q4 = u - row * 15;
                float ax = 0.f, ay = 0.f, az = 0.f, aw = 0.f;
                for (int L = 0; L < 48; ++L) {
                    const float4 v = e4[(size_t)L * (NB * 15) + u];
                    ax += v.x; ay += v.y; az += v.z; aw += v.w;
                }
                f16x4 h = {(f16)(ax*sc), (f16)(ay*sc), (f16)(az*sc), (f16)(aw*sc)};
                *(f16x4*)&x16[row][q4 * 4] = h;
            }
        }
    }

    // ---- per-wave weight fragments (B-frag elem e of lane l = W[kt*32+g*8+e][nt*16+r])
    f16x8 lf[2][8], gf[2][2], vf[2][2], f1f[2], f2f, f3f;
    float bl[8], bgv[2], bv0 = 0.f, bv1 = 0.f, bf1v[2], wf1se[2], bf2v = 0.f, bf3v = 0.f;
    float hD[2][4], VD[2][4], c[2][4] = {};
    float r0v[4] = {0.f, 0.f, 0.f, 0.f};     // head: rin0 staged in REGISTERS

    if (wid == 0) {      // spine: LSTM + gate + Wv weights; h0 -> REGISTERS only
        #pragma unroll
        for (int kt = 0; kt < 2; ++kt)
            #pragma unroll
            for (int tq = 0; tq < 8; ++tq) {
                const int gate = tq >> 1, j = (tq & 1) * 16 + r;
                const int trow = gate * 30 + j;
                f16x8 w;
                #pragma unroll
                for (int e = 0; e < 8; ++e) {
                    const int k = kt * 32 + g * 8 + e;
                    float val = 0.f;
                    if (j < 30) val = (k < 34) ? Wih[trow * 34 + k] : Whh[trow * 30 + (k - 34)];
                    w[e] = (f16)val;
                }
                lf[kt][tq] = w;
            }
        #pragma unroll
        for (int nt = 0; nt < 2; ++nt) {
            const int j = nt * 16 + r;
            f16x8 w0, w1;
            #pragma unroll
            for (int e = 0; e < 8; ++e) {
                const int kl = g * 8 + e;
                w0[e] = (f16)((j < 30 && kl >= 2) ? Wg[j * 60 + (kl - 2)] : 0.f);
                w1[e] = (f16)((j < 30 && kl < 30) ? Wg[j * 60 + 30 + kl] : 0.f);
            }
            gf[0][nt] = w0; gf[1][nt] = w1;
        }
        #pragma unroll
        for (int kt = 0; kt < 2; ++kt)
            #pragma unroll
            for (int nt = 0; nt < 2; ++nt) {
                const int j = nt * 16 + r;
                f16x8 w;
                #pragma unroll
                for (int e = 0; e < 8; ++e) {
                    const int kl = kt * 32 + g * 8 + e;
                    w[e] = (f16)((j < 30 && kl < 60) ? Wv[j * 60 + kl] : 0.f);
                }
                vf[kt][nt] = w;
            }
        #pragma unroll
        for (int tq = 0; tq < 8; ++tq) {
            const int gate = tq >> 1, j = (tq & 1) * 16 + r;
            bl[tq] = (j < 30) ? bih[gate * 30 + j] + bhh[gate * 30 + j] : 0.f;
        }
        #pragma unroll
        for (int nt = 0; nt < 2; ++nt) {
            const int j = nt * 16 + r;
            bgv[nt] = (j < 30) ? bg[j] : 0.f;
        }
        bv0 = bv[r];
        bv1 = (16 + r < 30) ? bv[16 + r] : 0.f;
        #pragma unroll
        for (int nt = 0; nt < 2; ++nt)       // h0 -> registers (x16 write deferred!)
            #pragma unroll
            for (int q = 0; q < 4; ++q) {
                const int row = 4 * g + q, j = nt * 16 + r;
                hD[nt][q] = (j < 30) ? hidden[(size_t)(bw + row) * 30 + j] : 0.f;
            }
    } else {             // head: fc weights; rin0 -> registers (x16 write deferred!)
        #pragma unroll
        for (int nt = 0; nt < 2; ++nt) {
            const int j = nt * 16 + r;
            f16x8 w;
            #pragma unroll
            for (int e = 0; e < 8; ++e) {
                const int kl = g * 8 + e;
                w[e] = (f16)((j < 30 && kl >= 2) ? Wf1[j * 31 + (kl - 2)] : 0.f);
            }
            f1f[nt] = w;
            bf1v[nt]  = (j < 30) ? bf1[j] : 0.f;
            wf1se[nt] = (j < 30) ? Wf1[j * 31 + 30] : 0.f;
        }
        #pragma unroll
        for (int e = 0; e < 8; ++e) {
            const int kl = g * 8 + e;
            f2f[e] = (f16)((r < 15 && kl < 30) ? Wf2[r * 30 + kl] : 0.f);
            f3f[e] = (f16)((r == 0 && kl < 15) ? Wf3[kl] : 0.f);
        }
        bf2v = (r < 15) ? bf2[r] : 0.f;
        bf3v = bf3[0];
        if (l < 16) {    // rin0 = nan_to_num(y[:,0,:]) -> registers
            const float* yp = y + (size_t)(bw + l) * 52;
            #pragma unroll
            for (int d = 0; d < 4; ++d) {
                float v = yp[d];
                r0v[d] = (v == v) ? v : 0.f;
            }
        }
    }
    __syncthreads();     // es fully staged & visible

    // ---- V = es @ Wv.T + bv (spine; reads x16 es cols 0..63 BEFORE any reuse)
    f16x8 va;
    if (wid == 0) {
        const f16x8 ea0 = *(const f16x8*)((const char*)x16 + (size_t)r * 144 + g * 16);
        const f16x8 ea1 = *(const f16x8*)((const char*)x16 + (size_t)r * 144 + 64 + g * 16);
        f32x4 vd0 = MFMA16(ea0, vf[0][0], kz); vd0 = MFMA16(ea1, vf[1][0], vd0);
        f32x4 vd1 = MFMA16(ea0, vf[0][1], kz); vd1 = MFMA16(ea1, vf[1][1], vd1);
        #pragma unroll
        for (int q = 0; q < 4; ++q) { VD[0][q] = vd0[q] + bv0; VD[1][q] = vd1[q] + bv1; }
        #pragma unroll
        for (int nt = 0; nt < 2; ++nt)
            #pragma unroll
            for (int q = 0; q < 4; ++q)
                z1b[4 * g + q][nt * 16 + r] = (f16)VD[nt][q];
        WBAR();
        va = *(const f16x8*)((const char*)z1b + (size_t)r * 64 + g * 16);
    }
    __syncthreads();     // es reads drained -> es region may be reused

    // ---- NOW overwrite the es region: h0 (spine, cols 34..63), rin0 (head, 0..3)
    if (wid == 0) {
        #pragma unroll
        for (int nt = 0; nt < 2; ++nt)
            #pragma unroll
            for (int q = 0; q < 4; ++q)
                x16[4 * g + q][34 + nt * 16 + r] = (f16)hD[nt][q];  // nt1 r>=14 -> scratch
    } else {
        if (l < 16) {
            #pragma unroll
            for (int d = 0; d < 4; ++d)
                x16[l][d] = (f16)r0v[d];
        }
    }
    // spine's A_1 reads its own h0 writes (same-wave order); head's rin0 is
    // consumed by B_1 only after the P1-end __syncthreads -> no barrier needed.

    // ---- 12-step pipelined recurrence ------------------------------------------
    float py1 = 0.f, py2 = 0.f, py3 = 0.f;   // head's y prefetch
    #pragma unroll 1
    for (int i = 1; i <= 12; ++i) {
        // P1: spine A_i  ||  head C/D/E of step i-1
        if (wid == 0) {
            // A: gate = sig([h|V] @ Wg.T + bg); enh -> x16 cols 4..33
            // (cols 32,33 stale values are zero-weighted in gf[0])
            const f16x8 xhg = *(const f16x8*)((const char*)x16 + (size_t)r * 144 + 64 + g * 16);
            f32x4 gd0 = MFMA16(xhg, gf[0][0], kz); gd0 = MFMA16(va, gf[1][0], gd0);
            f32x4 gd1 = MFMA16(xhg, gf[0][1], kz); gd1 = MFMA16(va, gf[1][1], gd1);
            #pragma unroll
            for (int nt = 0; nt < 2; ++nt)
                #pragma unroll
                for (int q = 0; q < 4; ++q) {
                    const float a  = (nt ? gd1[q] : gd0[q]) + bgv[nt];
                    const float gt = fast_sig(a);
                    const float enh = gt * hD[nt][q] + (1.f - gt) * VD[nt][q];
                    const int j = nt * 16 + r;
                    if (j < 30) x16[4 * g + q][4 + j] = (f16)enh;
                }
        } else if (i > 1) {
            const int s = i - 1;
            const float se = (float)s * (1.f / 12.f);
            // C: z1 = relu([h_s|se] @ Wf1.T + bf1)  (concurrent cols 32/33 writes
            // by spine A are finite f16 and zero-weighted in f1f -> safe)
            {
                const f16x8 hn = *(const f16x8*)((const char*)x16 + (size_t)r * 144 + 64 + g * 16);
                f32x4 d0 = MFMA16(hn, f1f[0], kz);
                f32x4 d1 = MFMA16(hn, f1f[1], kz);
                #pragma unroll
                for (int nt = 0; nt < 2; ++nt)
                    #pragma unroll
                    for (int q = 0; q < 4; ++q) {
                        const float z = fmaxf((nt ? d1[q] : d0[q]) + bf1v[nt] + se * wf1se[nt], 0.f);
                        z1b[4 * g + q][nt * 16 + r] = (f16)z;
                    }
            }
            WBAR();
            // D: z2 = relu(z1 @ Wf2.T + bf2) -> z1b cols 0..15
            {
                const f16x8 z1a = *(const f16x8*)((const char*)z1b + (size_t)r * 64 + g * 16);
                f32x4 d = MFMA16(z1a, f2f, kz);
                #pragma unroll
                for (int q = 0; q < 4; ++q)
                    z1b[4 * g + q][r] = (f16)fmaxf(d[q] + bf2v, 0.f);
            }
            WBAR();
            // E: out_s = z2 @ Wf3.T + bf3; rin_{s+1} = [y[:,s,1:4], out_s]
            {
                const f16x8 z2a = *(const f16x8*)((const char*)z1b + (size_t)r * 64 + g * 16);
                f32x4 od = MFMA16(z2a, f3f, kz);
                if (r == 0) {
                    #pragma unroll
                    for (int q = 0; q < 4; ++q) {
                        const float o = od[q] + bf3v;
                        out[(size_t)(s - 1) * NB + bw + 4 * g + q] = o;
                        x16[4 * g + q][3] = (f16)o;
                    }
                }
            }
            if (l < 16) {
                x16[l][0] = (f16)py1;
                x16[l][1] = (f16)py2;
                x16[l][2] = (f16)py3;
            }
        }
        __syncthreads();   // h_{i-1}+enh_i+rin_i all settled for B_i

        // P2: spine B_i  ||  head y-prefetch for step i
        if (wid == 0) {
            const f16x8 xa0 = *(const f16x8*)((const char*)x16 + (size_t)r * 144 + g * 16);
            const f16x8 xa1 = *(const f16x8*)((const char*)x16 + (size_t)r * 144 + 64 + g * 16);
            f32x4 ld[8];
            #pragma unroll
            for (int tq = 0; tq < 8; ++tq) {
                ld[tq] = MFMA16(xa0, lf[0][tq], kz);
                ld[tq] = MFMA16(xa1, lf[1][tq], ld[tq]);
            }
            #pragma unroll
            for (int jh = 0; jh < 2; ++jh)
                #pragma unroll
                for (int q = 0; q < 4; ++q) {
                    const float ii = fast_sig (ld[0 + jh][q] + bl[0 + jh]);
                    const float ff = fast_sig (ld[2 + jh][q] + bl[2 + jh]);
                    const float gg = fast_tanh(ld[4 + jh][q] + bl[4 + jh]);
                    const float oo = fast_sig (ld[6 + jh][q] + bl[6 + jh]);
                    const float cn = ff * c[jh][q] + ii * gg;
                    c[jh][q] = cn;
                    const float hn = oo * fast_tanh(cn);
                    hD[jh][q] = hn;
                    x16[4 * g + q][34 + jh * 16 + r] = (f16)hn;  // jh1 r>=14 -> scratch
                }
        } else {
            if (l < 16) {
                const float* yp = y + (size_t)(bw + l) * 52 + (size_t)i * 4;
                py1 = yp[1]; py2 = yp[2]; py3 = yp[3];
            }
        }
        __syncthreads();   // h_i visible for head's CDE_i and spine's A_{i+1}
    }

    // ---- epilogue: head finishes C/D/E of step 12
    if (wid == 1) {
        const float se = 1.0f;
        {
            const f16x8 hn = *(const f16x8*)((const char*)x16 + (size_t)r * 144 + 64 + g * 16);
            f32x4 d0 = MFMA16(hn, f1f[0], kz);
            f32x4 d1 = MFMA16(hn, f1f[1], kz);
            #pragma unroll
            for (int nt = 0; nt < 2; ++nt)
                #pragma unroll
                for (int q = 0; q < 4; ++q) {
                    const float z = fmaxf((nt ? d1[q] : d0[q]) + bf1v[nt] + se * wf1se[nt], 0.f);
                    z1b[4 * g + q][nt * 16 + r] = (f16)z;
                }
        }
        WBAR();
        {
            const f16x8 z1a = *(const f16x8*)((const char*)z1b + (size_t)r * 64 + g * 16);
            f32x4 d = MFMA16(z1a, f2f, kz);
            #pragma unroll
            for (int q = 0; q < 4; ++q)
                z1b[4 * g + q][r] = (f16)fmaxf(d[q] + bf2v, 0.f);
        }
        WBAR();
        {
            const f16x8 z2a = *(const f16x8*)((const char*)z1b + (size_t)r * 64 + g * 16);
            f32x4 od = MFMA16(z2a, f3f, kz);
            if (r == 0) {
                #pragma unroll
                for (int q = 0; q < 4; ++q)
                    out[(size_t)11 * NB + bw + 4 * g + q] = od[q] + bf3v;
            }
        }
    }
}

extern "C" void kernel_launch(void* const* d_in, const int* in_sizes, int n_in,
                              void* d_out, int out_size, void* d_ws, size_t ws_size,
                              hipStream_t stream) {
    (void)in_sizes; (void)n_in; (void)out_size;
    // 0 batch_ids, 1 y, 2 encoder_outputs, 3 hidden, 4 Wq, 5 bq, 6 Wk, 7 bk,
    // 8 Wv, 9 bv, 10 Wsa1, 11 bsa1, 12 Wsa2, 13 bsa2, 14 Wg, 15 bg,
    // 16 Wf1, 17 bf1, 18 Wf2, 19 bf2, 20 Wf3, 21 bf3, 22 W_ih, 23 b_ih,
    // 24 W_hh, 25 b_hh.  (Wq/bq/Wk/bk/Wsa* dead: softmax over size-1 axis == 1)
    const float* enc = (const float*)d_in[2];
    const size_t es_bytes = (size_t)NB * 60 * sizeof(float);
    float* es = (ws_size >= es_bytes) ? (float*)d_ws : nullptr;

    if (es) {
        es_kernel<<<dim3(NB * 15 / 256), dim3(256), 0, stream>>>(enc, es);
    }
    decoder_kernel<<<dim3(NB / 16), dim3(128), 0, stream>>>(
        (const float*)d_in[1],  enc, es, (const float*)d_in[3],
        (const float*)d_in[8],  (const float*)d_in[9],
        (const float*)d_in[14], (const float*)d_in[15],
        (const float*)d_in[16], (const float*)d_in[17],
        (const float*)d_in[18], (const float*)d_in[19],
        (const float*)d_in[20], (const float*)d_in[21],
        (const float*)d_in[22], (const float*)d_in[23],
        (const float*)d_in[24], (const float*)d_in[25],
        (float*)d_out);
}